// Round 2
// baseline (1380.537 us; speedup 1.0000x reference)
//
#include <hip/hip_runtime.h>
#include <hip/hip_bf16.h>

#define N_NODES 100000
#define N_EDGES 3200000
#define NUM_GRAPHS 128
#define HIDDEN 32

// ---------------------------------------------------------------------------
// Kernel 1: scalar edge aggregation  agg1[dst] += x[src]
// ---------------------------------------------------------------------------
__global__ void k_edge_agg1(const float* __restrict__ x,
                            const int* __restrict__ src,
                            const int* __restrict__ dst,
                            float* __restrict__ agg1) {
    int e = blockIdx.x * blockDim.x + threadIdx.x;
    if (e < N_EDGES) {
        atomicAdd(&agg1[dst[e]], x[src[e]]);
    }
}

// ---------------------------------------------------------------------------
// Kernel 2: s[i] = agg1[i] + x[i]   (fold self term; s is the scalar that
// fully determines the layer-1 output h[i][k] = relu(s*W1[k]+b1[k]))
// ---------------------------------------------------------------------------
__global__ void k_add_x(const float* __restrict__ x, float* __restrict__ s) {
    int i = blockIdx.x * blockDim.x + threadIdx.x;
    if (i < N_NODES) s[i] += x[i];
}

// ---------------------------------------------------------------------------
// Kernel 3: layer-2 edge aggregation.
// 32 lanes per edge; lane k recomputes h[src][k] from the scalar s[src]
// (1 gather instead of a 128B row gather) and atomically accumulates into
// agg2[dst*32+k] (contiguous 128B line per edge).
// ---------------------------------------------------------------------------
__global__ void k_edge_agg2(const float* __restrict__ s,
                            const int* __restrict__ src,
                            const int* __restrict__ dst,
                            const float* __restrict__ W1,
                            const float* __restrict__ b1,
                            float* __restrict__ agg2) {
    long long t = (long long)blockIdx.x * blockDim.x + threadIdx.x;
    int e = (int)(t >> 5);
    int k = (int)(t & 31);
    if (e < N_EDGES) {
        int sn = src[e];
        int dn = dst[e];
        float sv = s[sn];
        float h = fmaxf(sv * W1[k] + b1[k], 0.0f);
        atomicAdd(&agg2[dn * HIDDEN + k], h);
    }
}

// ---------------------------------------------------------------------------
// Kernel 4: per-node layer-2 matvec + ReLU + pool scatter.
// 32 lanes per node. lane k holds v_k = h[i][k] + agg2[i][k]; the 32x32
// matvec uses __shfl broadcast over the 32-lane subgroup. Result atomically
// pooled into pool[batch[i]*32 + k].
// ---------------------------------------------------------------------------
__global__ void k_node_out(const float* __restrict__ s,
                           const float* __restrict__ agg2,
                           const int* __restrict__ batch,
                           const float* __restrict__ W1,
                           const float* __restrict__ b1,
                           const float* __restrict__ W2,
                           const float* __restrict__ b2,
                           float* __restrict__ pool) {
    long long t = (long long)blockIdx.x * blockDim.x + threadIdx.x;
    int i = (int)(t >> 5);
    int k = (int)(t & 31);
    if (i >= N_NODES) return;
    float sv = s[i];
    float vk = fmaxf(sv * W1[k] + b1[k], 0.0f) + agg2[i * HIDDEN + k];
    float acc = b2[k];
#pragma unroll
    for (int j = 0; j < 32; ++j) {
        float vj = __shfl(vk, j, 32);
        acc += vj * W2[j * HIDDEN + k];
    }
    float outk = fmaxf(acc, 0.0f);
    atomicAdd(&pool[batch[i] * HIDDEN + k], outk);
}

// ---------------------------------------------------------------------------
// Kernel 5: out = |pool1 - pool2|
// ---------------------------------------------------------------------------
__global__ void k_absdiff(const float* __restrict__ pool, float* __restrict__ out) {
    int i = blockIdx.x * blockDim.x + threadIdx.x;
    if (i < NUM_GRAPHS * HIDDEN) {
        out[i] = fabsf(pool[i] - pool[NUM_GRAPHS * HIDDEN + i]);
    }
}

extern "C" void kernel_launch(void* const* d_in, const int* in_sizes, int n_in,
                              void* d_out, int out_size, void* d_ws, size_t ws_size,
                              hipStream_t stream) {
    const float* x1     = (const float*)d_in[0];
    const int*   ei1    = (const int*)d_in[1];   // [2, N_EDGES] flattened: src row then dst row
    const int*   batch1 = (const int*)d_in[2];
    const float* x2     = (const float*)d_in[3];
    const int*   ei2    = (const int*)d_in[4];
    const int*   batch2 = (const int*)d_in[5];
    const float* W1     = (const float*)d_in[6];
    const float* b1     = (const float*)d_in[7];
    const float* W2     = (const float*)d_in[8];
    const float* b2     = (const float*)d_in[9];
    float* out = (float*)d_out;

    // workspace layout (reused across the two graphs; stream order serializes)
    char* ws = (char*)d_ws;
    size_t off = 0;
    float* s_buf = (float*)(ws + off);                       // N floats
    off += ((size_t)N_NODES * 4 + 255) & ~(size_t)255;
    float* agg2  = (float*)(ws + off);                       // N*32 floats
    off += ((size_t)N_NODES * HIDDEN * 4 + 255) & ~(size_t)255;
    float* pool  = (float*)(ws + off);                       // 2*128*32 floats
    off += (size_t)2 * NUM_GRAPHS * HIDDEN * 4;

    hipMemsetAsync(pool, 0, (size_t)2 * NUM_GRAPHS * HIDDEN * 4, stream);

    for (int g = 0; g < 2; ++g) {
        const float* x    = g ? x2 : x1;
        const int* src    = g ? ei2 : ei1;
        const int* dst    = src + N_EDGES;
        const int* batch  = g ? batch2 : batch1;
        float* poolg = pool + (size_t)g * NUM_GRAPHS * HIDDEN;

        hipMemsetAsync(s_buf, 0, (size_t)N_NODES * 4, stream);
        hipMemsetAsync(agg2, 0, (size_t)N_NODES * HIDDEN * 4, stream);

        k_edge_agg1<<<(N_EDGES + 255) / 256, 256, 0, stream>>>(x, src, dst, s_buf);
        k_add_x<<<(N_NODES + 255) / 256, 256, 0, stream>>>(x, s_buf);

        long long t2 = (long long)N_EDGES * 32;
        k_edge_agg2<<<(unsigned)((t2 + 255) / 256), 256, 0, stream>>>(
            s_buf, src, dst, W1, b1, agg2);

        long long t3 = (long long)N_NODES * 32;
        k_node_out<<<(unsigned)((t3 + 255) / 256), 256, 0, stream>>>(
            s_buf, agg2, batch, W1, b1, W2, b2, poolg);
    }

    k_absdiff<<<(NUM_GRAPHS * HIDDEN + 255) / 256, 256, 0, stream>>>(pool, out);
}

// Round 4
// 1300.636 us; speedup vs baseline: 1.0614x; 1.0614x over previous
//
#include <hip/hip_runtime.h>
#include <hip/hip_bf16.h>
#include <math.h>

#define N_NODES 100000
#define N_EDGES 3200000
#define NUM_GRAPHS 128
#define HIDDEN 32
#define NBUCKET 33   // 32 sorted thresholds -> 33 buckets

// ---------------------------------------------------------------------------
// Kernel 1: scalar edge aggregation  s[dst] += x[src]   (layer-1 sum)
// ---------------------------------------------------------------------------
__global__ void k_edge_agg1(const float* __restrict__ x,
                            const int* __restrict__ src,
                            const int* __restrict__ dst,
                            float* __restrict__ s) {
    int e = blockIdx.x * blockDim.x + threadIdx.x;
    if (e < N_EDGES) {
        atomicAdd(&s[dst[e]], x[src[e]]);
    }
}

// ---------------------------------------------------------------------------
// Kernel 2: s[i] += x[i]  (fold self term; s fully determines layer-1 output)
// ---------------------------------------------------------------------------
__global__ void k_add_x(const float* __restrict__ x, float* __restrict__ s) {
    int i = blockIdx.x * blockDim.x + threadIdx.x;
    if (i < N_NODES) s[i] += x[i];
}

// ---------------------------------------------------------------------------
// Setup (once): thresholds t_k = -b1k/W1k, sorted; per-k first-equal index m_k
// and sign class. relu(s*W1k+b1k) = W1k*s+b1k active iff s>t_k (W1k>0) or
// s<t_k (W1k<0); equality contributes exactly 0 so boundaries are safe.
// ---------------------------------------------------------------------------
__global__ void k_setup(const float* __restrict__ W1, const float* __restrict__ b1,
                        float* __restrict__ ts, int* __restrict__ mk,
                        int* __restrict__ cls) {
    __shared__ float t[32];
    __shared__ float tso[32];
    int k = threadIdx.x;
    if (k < 32) {
        float w = W1[k], bb = b1[k];
        int c = (w > 0.f) ? 1 : ((w < 0.f) ? -1 : 0);
        t[k] = (c == 0) ? INFINITY : (-bb / w);
        cls[k] = c;
    }
    __syncthreads();
    if (threadIdx.x == 0) {
        float a[32];
        for (int i = 0; i < 32; ++i) a[i] = t[i];
        for (int i = 1; i < 32; ++i) {               // insertion sort (32 elems)
            float key = a[i]; int j = i - 1;
            while (j >= 0 && a[j] > key) { a[j + 1] = a[j]; --j; }
            a[j + 1] = key;
        }
        for (int i = 0; i < 32; ++i) { tso[i] = a[i]; ts[i] = a[i]; }
    }
    __syncthreads();
    if (k < 32) {
        float tk = t[k];
        int m = 0;                                   // first index equal to tk
        for (int i = 0; i < 32; ++i) m += (tso[i] < tk) ? 1 : 0;
        mk[k] = m;
    }
}

// ---------------------------------------------------------------------------
// Kernel 3: per-edge bucket histogram. bucket b = #{t_sorted < s[src]} via
// binary search; TWO atomics per edge (sum,count packed adjacent)
// instead of 32 -> atomic payload 25.6 MB instead of 409 MB.
// hist layout: float2 slab-major [NBUCKET][N_NODES] -> hot extreme buckets
// stay cache-resident.
// ---------------------------------------------------------------------------
__global__ void k_edge_hist(const float* __restrict__ s,
                            const int* __restrict__ src,
                            const int* __restrict__ dst,
                            const float* __restrict__ ts,
                            float* __restrict__ hist) {
    __shared__ float t[32];
    if (threadIdx.x < 32) t[threadIdx.x] = ts[threadIdx.x];
    __syncthreads();
    int e = blockIdx.x * blockDim.x + threadIdx.x;
    if (e >= N_EDGES) return;
    float sv = s[src[e]];
    int dn = dst[e];
    int b = 0;
    if (t[31] < sv) {
        b = 32;
    } else {
#pragma unroll
        for (int st = 16; st; st >>= 1)
            if (b + st <= 32 && t[b + st - 1] < sv) b += st;
    }
    size_t idx = 2 * ((size_t)b * N_NODES + dn);
    atomicAdd(&hist[idx], sv);
    atomicAdd(&hist[idx + 1], 1.0f);
}

// ---------------------------------------------------------------------------
// Kernel 4: one 64-lane wave per node. Lanes 0..32 load the (sum,cnt)
// histogram row; wave suffix-scan reconstructs S_above/C_above at every
// threshold; lane k rebuilds agg2[i][k] exactly, adds h_i[k], does the 32x32
// W2 matvec via shfl broadcast, ReLU, pools by graph id.
// ---------------------------------------------------------------------------
__global__ void k_node_out(const float* __restrict__ s,
                           const float* __restrict__ hist,
                           const int* __restrict__ batch,
                           const float* __restrict__ W1,
                           const float* __restrict__ b1,
                           const float* __restrict__ W2,
                           const float* __restrict__ b2,
                           const int* __restrict__ mk,
                           const int* __restrict__ cls,
                           float* __restrict__ pool) {
    int lane = threadIdx.x & 63;
    int i = blockIdx.x * (blockDim.x >> 6) + (threadIdx.x >> 6);
    if (i >= N_NODES) return;

    float Tsum = 0.f, Tcnt = 0.f;
    if (lane < NBUCKET) {
        float2 v = ((const float2*)hist)[(size_t)lane * N_NODES + i];
        Tsum = v.x; Tcnt = v.y;
    }
    // inclusive suffix sum across lanes (lanes >= 33 hold 0)
#pragma unroll
    for (int d = 1; d < 64; d <<= 1) {
        float a = __shfl_down(Tsum, d, 64);
        float c = __shfl_down(Tcnt, d, 64);
        if (lane + d < 64) { Tsum += a; Tcnt += c; }
    }
    float totS = __shfl(Tsum, 0, 64);
    float totC = __shfl(Tcnt, 0, 64);
    float si = s[i];

    int k = lane & 31;
    float w = W1[k], bb = b1[k];
    int c = cls[k], m = mk[k];
    float SA = __shfl(Tsum, m + 1, 64);   // sum over buckets > m  (s > t_k)
    float CA = __shfl(Tcnt, m + 1, 64);
    float agg;
    if (c > 0)      agg = w * SA + bb * CA;
    else if (c < 0) agg = w * (totS - SA) + bb * (totC - CA);
    else            agg = fmaxf(bb, 0.f) * totC;

    float v = fmaxf(fmaf(si, w, bb), 0.f) + agg;   // h_i[k] + agg2[i][k]
    float acc = b2[k];
#pragma unroll
    for (int j = 0; j < 32; ++j) {
        float vj = __shfl(v, j, 64);               // dims j live in lanes 0..31
        acc = fmaf(vj, W2[j * HIDDEN + k], acc);
    }
    if (lane < 32)
        atomicAdd(&pool[(size_t)batch[i] * HIDDEN + k], fmaxf(acc, 0.f));
}

// ---------------------------------------------------------------------------
// Kernel 5: out = |pool1 - pool2|
// ---------------------------------------------------------------------------
__global__ void k_absdiff(const float* __restrict__ pool, float* __restrict__ out) {
    int i = blockIdx.x * blockDim.x + threadIdx.x;
    if (i < NUM_GRAPHS * HIDDEN)
        out[i] = fabsf(pool[i] - pool[NUM_GRAPHS * HIDDEN + i]);
}

extern "C" void kernel_launch(void* const* d_in, const int* in_sizes, int n_in,
                              void* d_out, int out_size, void* d_ws, size_t ws_size,
                              hipStream_t stream) {
    const float* x1     = (const float*)d_in[0];
    const int*   ei1    = (const int*)d_in[1];   // [2, N_EDGES]: src row, dst row
    const int*   batch1 = (const int*)d_in[2];
    const float* x2     = (const float*)d_in[3];
    const int*   ei2    = (const int*)d_in[4];
    const int*   batch2 = (const int*)d_in[5];
    const float* W1     = (const float*)d_in[6];
    const float* b1     = (const float*)d_in[7];
    const float* W2     = (const float*)d_in[8];
    const float* b2     = (const float*)d_in[9];
    float* out = (float*)d_out;

    // workspace layout
    char* ws = (char*)d_ws;
    size_t off = 0;
    float* s_buf = (float*)(ws + off);                       // N floats
    off += (((size_t)N_NODES * 4) + 255) & ~(size_t)255;
    float* hist  = (float*)(ws + off);                       // NBUCKET*N*2 floats
    size_t hist_bytes = (size_t)NBUCKET * N_NODES * 2 * 4;   // 26.4 MB
    off += (hist_bytes + 255) & ~(size_t)255;
    float* pool  = (float*)(ws + off);                       // 2*128*32 floats
    off += (((size_t)2 * NUM_GRAPHS * HIDDEN * 4) + 255) & ~(size_t)255;
    float* ts    = (float*)(ws + off); off += 256;           // sorted thresholds
    int*   mk    = (int*)(ws + off);   off += 256;
    int*   cls   = (int*)(ws + off);   off += 256;

    hipMemsetAsync(pool, 0, (size_t)2 * NUM_GRAPHS * HIDDEN * 4, stream);
    k_setup<<<1, 64, 0, stream>>>(W1, b1, ts, mk, cls);

    for (int g = 0; g < 2; ++g) {
        const float* x    = g ? x2 : x1;
        const int* src    = g ? ei2 : ei1;
        const int* dst    = src + N_EDGES;
        const int* batch  = g ? batch2 : batch1;
        float* poolg = pool + (size_t)g * NUM_GRAPHS * HIDDEN;

        hipMemsetAsync(s_buf, 0, (size_t)N_NODES * 4, stream);
        hipMemsetAsync(hist, 0, hist_bytes, stream);

        k_edge_agg1<<<(N_EDGES + 255) / 256, 256, 0, stream>>>(x, src, dst, s_buf);
        k_add_x<<<(N_NODES + 255) / 256, 256, 0, stream>>>(x, s_buf);

        k_edge_hist<<<(N_EDGES + 255) / 256, 256, 0, stream>>>(s_buf, src, dst, ts, hist);

        int waves_per_block = 256 / 64;
        int nblk = (N_NODES + waves_per_block - 1) / waves_per_block;
        k_node_out<<<nblk, 256, 0, stream>>>(s_buf, hist, batch,
                                             W1, b1, W2, b2, mk, cls, poolg);
    }

    k_absdiff<<<(NUM_GRAPHS * HIDDEN + 255) / 256, 256, 0, stream>>>(pool, out);
}

// Round 7
// 599.640 us; speedup vs baseline: 2.3023x; 2.1690x over previous
//
#include <hip/hip_runtime.h>
#include <hip/hip_bf16.h>
#include <math.h>

#define N_NODES 100000
#define N_EDGES 3200000
#define NUM_GRAPHS 128
#define HIDDEN 32
#define NB 33              // 32 sorted thresholds -> 33 value-buckets
#define NPB 128            // nodes per coarse bucket (dst >> 7)
#define NBKT 782           // ceil(100000 / 128)
#define NCHUNK 256         // edge chunks for binning
#define EPC (N_EDGES / NCHUNK)   // 12500 exactly
#define SRC_BITS 17
#define SRC_MASK 0x1FFFF

// ---------------------------------------------------------------------------
// Setup (once): thresholds t_k = -b1k/W1k sorted; per-k first-equal index m_k
// and sign class. relu(s*W1k+b1k) active iff s>t_k (W1k>0) or s<t_k (W1k<0).
// ---------------------------------------------------------------------------
__global__ void k_setup(const float* __restrict__ W1, const float* __restrict__ b1,
                        float* __restrict__ ts, int* __restrict__ mk,
                        int* __restrict__ cls) {
    __shared__ float t[32];
    __shared__ float tso[32];
    int k = threadIdx.x;
    if (k < 32) {
        float w = W1[k], bb = b1[k];
        int c = (w > 0.f) ? 1 : ((w < 0.f) ? -1 : 0);
        t[k] = (c == 0) ? INFINITY : (-bb / w);
        cls[k] = c;
    }
    __syncthreads();
    if (threadIdx.x == 0) {
        float a[32];
        for (int i = 0; i < 32; ++i) a[i] = t[i];
        for (int i = 1; i < 32; ++i) {
            float key = a[i]; int j = i - 1;
            while (j >= 0 && a[j] > key) { a[j + 1] = a[j]; --j; }
            a[j + 1] = key;
        }
        for (int i = 0; i < 32; ++i) { tso[i] = a[i]; ts[i] = a[i]; }
    }
    __syncthreads();
    if (k < 32) {
        float tk = t[k];
        int m = 0;
        for (int i = 0; i < 32; ++i) m += (tso[i] < tk) ? 1 : 0;
        mk[k] = m;
    }
}

// ---------------------------------------------------------------------------
// Binning pass 1: per-chunk bucket counts (LDS histogram, coalesced store)
// ---------------------------------------------------------------------------
__global__ void k_count(const int* __restrict__ dst, unsigned* __restrict__ Cmat) {
    __shared__ unsigned cnt[NBKT];
    for (int b = threadIdx.x; b < NBKT; b += blockDim.x) cnt[b] = 0u;
    __syncthreads();
    int blk = blockIdx.x;
    for (int e = blk * EPC + threadIdx.x; e < (blk + 1) * EPC; e += blockDim.x)
        atomicAdd(&cnt[((unsigned)dst[e]) >> 7], 1u);
    __syncthreads();
    for (int b = threadIdx.x; b < NBKT; b += blockDim.x)
        Cmat[(size_t)b * NCHUNK + blk] = cnt[b];
}

// ---------------------------------------------------------------------------
// Binning pass 2a: per-bucket exclusive scan over chunks + row total
// ---------------------------------------------------------------------------
__global__ void k_rowscan(const unsigned* __restrict__ Cmat, unsigned* __restrict__ Omat,
                          unsigned* __restrict__ Btot) {
    __shared__ unsigned sh[NCHUNK];
    int b = blockIdx.x, t = threadIdx.x;
    unsigned v = Cmat[(size_t)b * NCHUNK + t];
    sh[t] = v; __syncthreads();
    for (int d = 1; d < NCHUNK; d <<= 1) {
        unsigned a = (t >= d) ? sh[t - d] : 0u; __syncthreads();
        sh[t] += a; __syncthreads();
    }
    Omat[(size_t)b * NCHUNK + t] = sh[t] - v;          // exclusive prefix
    if (t == NCHUNK - 1) Btot[b] = sh[t];
}

// ---------------------------------------------------------------------------
// Binning pass 2b: exclusive scan of bucket totals -> bucket bases
// ---------------------------------------------------------------------------
__global__ void k_bscan(const unsigned* __restrict__ Btot, unsigned* __restrict__ Bbase) {
    __shared__ unsigned sh[1024];
    int t = threadIdx.x;
    unsigned v = (t < NBKT) ? Btot[t] : 0u;
    sh[t] = v; __syncthreads();
    for (int d = 1; d < 1024; d <<= 1) {
        unsigned a = (t >= d) ? sh[t - d] : 0u; __syncthreads();
        sh[t] += a; __syncthreads();
    }
    if (t < NBKT) Bbase[t] = sh[t] - v;
}

// ---------------------------------------------------------------------------
// Binning pass 3: scatter packed (dst_local<<17 | src) into bucket-contiguous
// storage. Only LDS atomics for cursors; global writes are plain stores.
// ---------------------------------------------------------------------------
__global__ void k_scatter(const int* __restrict__ src, const int* __restrict__ dst,
                          const unsigned* __restrict__ Omat,
                          const unsigned* __restrict__ Bbase,
                          unsigned* __restrict__ binned) {
    __shared__ unsigned cur[NBKT];
    int blk = blockIdx.x;
    for (int b = threadIdx.x; b < NBKT; b += blockDim.x)
        cur[b] = Bbase[b] + Omat[(size_t)b * NCHUNK + blk];
    __syncthreads();
    for (int e = blk * EPC + threadIdx.x; e < (blk + 1) * EPC; e += blockDim.x) {
        unsigned d = (unsigned)dst[e];
        unsigned p = atomicAdd(&cur[d >> 7], 1u);
        binned[p] = ((d & 127u) << SRC_BITS) | (unsigned)src[e];
    }
}

// ---------------------------------------------------------------------------
// Layer 1: per-bucket LDS segment-sum  s[i] = x[i] + sum_{j->i} x[j]
// ---------------------------------------------------------------------------
__global__ void k_layer1(const float* __restrict__ x, const unsigned* __restrict__ binned,
                         const unsigned* __restrict__ Bbase, const unsigned* __restrict__ Btot,
                         float* __restrict__ s) {
    __shared__ float sloc[NPB];
    int b = blockIdx.x;
    if (threadIdx.x < NPB) sloc[threadIdx.x] = 0.f;
    __syncthreads();
    unsigned beg = Bbase[b], n = Btot[b];
    for (unsigned i = threadIdx.x; i < n; i += blockDim.x) {
        unsigned p = binned[beg + i];
        atomicAdd(&sloc[p >> SRC_BITS], x[p & SRC_MASK]);
    }
    __syncthreads();
    if (threadIdx.x < NPB) {
        int node = b * NPB + threadIdx.x;
        if (node < N_NODES) s[node] = sloc[threadIdx.x] + x[node];
    }
}

// ---------------------------------------------------------------------------
// Layer 2 fused: per-bucket LDS (sum,count)[128][33] histogram of source
// scalars, then per-node suffix-scan reconstruction + W2 matvec + ReLU +
// register-accumulated pool flush (batch is sorted -> 1-2 flushes per wave).
// ---------------------------------------------------------------------------
__global__ void k_layer2(const float* __restrict__ s, const unsigned* __restrict__ binned,
                         const unsigned* __restrict__ Bbase, const unsigned* __restrict__ Btot,
                         const int* __restrict__ batch,
                         const float* __restrict__ ts, const int* __restrict__ mk,
                         const int* __restrict__ cls,
                         const float* __restrict__ W1, const float* __restrict__ b1,
                         const float* __restrict__ W2, const float* __restrict__ b2,
                         float* __restrict__ pool) {
    __shared__ float hS[NPB * NB];
    __shared__ float hC[NPB * NB];
    __shared__ float t_s[32];
    __shared__ float w2s[32 * 32];
    int tid = threadIdx.x;
    for (int i = tid; i < NPB * NB; i += blockDim.x) { hS[i] = 0.f; hC[i] = 0.f; }
    if (tid < 32) t_s[tid] = ts[tid];
    for (int i = tid; i < 32 * 32; i += blockDim.x) w2s[i] = W2[i];
    __syncthreads();

    int b = blockIdx.x;
    unsigned beg = Bbase[b], n = Btot[b];
    for (unsigned i = tid; i < n; i += blockDim.x) {
        unsigned p = binned[beg + i];
        float sv = s[p & SRC_MASK];
        unsigned dl = p >> SRC_BITS;
        int bk = 0;
        if (t_s[31] < sv) bk = 32;
        else {
#pragma unroll
            for (int st = 16; st; st >>= 1)
                if (bk + st <= 32 && t_s[bk + st - 1] < sv) bk += st;
        }
        atomicAdd(&hS[dl * NB + bk], sv);
        atomicAdd(&hC[dl * NB + bk], 1.0f);
    }
    __syncthreads();

    int wv = tid >> 6, lane = tid & 63, k = lane & 31;
    float w = W1[k], bb = b1[k], b2k = b2[k];
    int c = cls[k], m1 = mk[k] + 1;
    float pacc = 0.f; int curg = -1;
    for (int t = wv * 16; t < wv * 16 + 16; ++t) {
        int node = b * NPB + t;
        if (node >= N_NODES) break;                // uniform across the wave
        float Tsum = 0.f, Tcnt = 0.f;
        if (lane < NB) { Tsum = hS[t * NB + lane]; Tcnt = hC[t * NB + lane]; }
#pragma unroll
        for (int d2 = 1; d2 < 64; d2 <<= 1) {      // inclusive suffix sum
            float a  = __shfl_down(Tsum, d2, 64);
            float cc = __shfl_down(Tcnt, d2, 64);
            if (lane + d2 < 64) { Tsum += a; Tcnt += cc; }
        }
        float totS = __shfl(Tsum, 0, 64), totC = __shfl(Tcnt, 0, 64);
        float SA = __shfl(Tsum, m1, 64), CA = __shfl(Tcnt, m1, 64);
        float agg;
        if (c > 0)      agg = w * SA + bb * CA;
        else if (c < 0) agg = w * (totS - SA) + bb * (totC - CA);
        else            agg = fmaxf(bb, 0.f) * totC;
        float si = s[node];
        float v = fmaxf(fmaf(si, w, bb), 0.f) + agg;   // h_i[k] + agg2[i][k]
        float acc = b2k;
#pragma unroll
        for (int j = 0; j < 32; ++j)
            acc = fmaf(__shfl(v, j, 64), w2s[j * 32 + k], acc);
        float outk = fmaxf(acc, 0.f);
        int g = batch[node];
        if (g != curg) {
            if (curg >= 0 && lane < 32) atomicAdd(&pool[curg * HIDDEN + k], pacc);
            pacc = 0.f; curg = g;
        }
        pacc += outk;
    }
    if (curg >= 0 && lane < 32) atomicAdd(&pool[curg * HIDDEN + k], pacc);
}

// ---------------------------------------------------------------------------
// out = |pool1 - pool2|
// ---------------------------------------------------------------------------
__global__ void k_absdiff(const float* __restrict__ pool, float* __restrict__ out) {
    int i = blockIdx.x * blockDim.x + threadIdx.x;
    if (i < NUM_GRAPHS * HIDDEN)
        out[i] = fabsf(pool[i] - pool[NUM_GRAPHS * HIDDEN + i]);
}

extern "C" void kernel_launch(void* const* d_in, const int* in_sizes, int n_in,
                              void* d_out, int out_size, void* d_ws, size_t ws_size,
                              hipStream_t stream) {
    const float* x1     = (const float*)d_in[0];
    const int*   ei1    = (const int*)d_in[1];   // [2, N_EDGES]: src row, dst row
    const int*   batch1 = (const int*)d_in[2];
    const float* x2     = (const float*)d_in[3];
    const int*   ei2    = (const int*)d_in[4];
    const int*   batch2 = (const int*)d_in[5];
    const float* W1     = (const float*)d_in[6];
    const float* b1     = (const float*)d_in[7];
    const float* W2     = (const float*)d_in[8];
    const float* b2     = (const float*)d_in[9];
    float* out = (float*)d_out;

    // workspace layout (~15 MB)
    char* ws = (char*)d_ws;
    size_t off = 0;
    auto alloc = [&](size_t bytes) { char* p = ws + off; off += (bytes + 255) & ~(size_t)255; return p; };
    float*    s_buf  = (float*)   alloc((size_t)N_NODES * 4);
    unsigned* binned = (unsigned*)alloc((size_t)N_EDGES * 4);
    unsigned* Cmat   = (unsigned*)alloc((size_t)NBKT * NCHUNK * 4);
    unsigned* Omat   = (unsigned*)alloc((size_t)NBKT * NCHUNK * 4);
    unsigned* Btot   = (unsigned*)alloc((size_t)NBKT * 4);
    unsigned* Bbase  = (unsigned*)alloc((size_t)NBKT * 4);
    float*    pool   = (float*)   alloc((size_t)2 * NUM_GRAPHS * HIDDEN * 4);
    float*    ts     = (float*)   alloc(256);
    int*      mk     = (int*)     alloc(256);
    int*      cls    = (int*)     alloc(256);

    hipMemsetAsync(pool, 0, (size_t)2 * NUM_GRAPHS * HIDDEN * 4, stream);
    k_setup<<<1, 64, 0, stream>>>(W1, b1, ts, mk, cls);

    for (int g = 0; g < 2; ++g) {
        const float* x   = g ? x2 : x1;
        const int* src   = g ? ei2 : ei1;
        const int* dst   = src + N_EDGES;
        const int* batch = g ? batch2 : batch1;
        float* poolg = pool + (size_t)g * NUM_GRAPHS * HIDDEN;

        k_count  <<<NCHUNK, 256, 0, stream>>>(dst, Cmat);
        k_rowscan<<<NBKT,   256, 0, stream>>>(Cmat, Omat, Btot);
        k_bscan  <<<1,     1024, 0, stream>>>(Btot, Bbase);
        k_scatter<<<NCHUNK, 256, 0, stream>>>(src, dst, Omat, Bbase, binned);
        k_layer1 <<<NBKT,   512, 0, stream>>>(x, binned, Bbase, Btot, s_buf);
        k_layer2 <<<NBKT,   512, 0, stream>>>(s_buf, binned, Bbase, Btot, batch,
                                              ts, mk, cls, W1, b1, W2, b2, poolg);
    }

    k_absdiff<<<(NUM_GRAPHS * HIDDEN + 255) / 256, 256, 0, stream>>>(pool, out);
}

// Round 10
// 488.903 us; speedup vs baseline: 2.8237x; 1.2265x over previous
//
#include <hip/hip_runtime.h>
#include <hip/hip_bf16.h>
#include <math.h>

#define N_NODES 100000
#define N_EDGES 3200000
#define NUM_GRAPHS 128
#define HIDDEN 32
#define NB 33              // 32 sorted thresholds -> 33 value-buckets
#define NPB 128            // nodes per coarse bucket (dst >> 7)
#define NBKT 782           // ceil(100000 / 128)
#define NCHUNK 256         // edge chunks per graph
#define EPC (N_EDGES / NCHUNK)   // 12500 exactly
#define SRC_BITS 17
#define SRC_MASK 0x1FFFF
#define S_STRIDE 100096    // per-graph stride of s buffer (aligned)

// ---------------------------------------------------------------------------
// Setup (once): thresholds t_k = -b1k/W1k sorted; per-k first-equal index m_k
// and sign class. relu(s*W1k+b1k) active iff s>t_k (W1k>0) or s<t_k (W1k<0).
// ---------------------------------------------------------------------------
__global__ void k_setup(const float* __restrict__ W1, const float* __restrict__ b1,
                        float* __restrict__ ts, int* __restrict__ mk,
                        int* __restrict__ cls) {
    __shared__ float t[32];
    __shared__ float tso[32];
    int k = threadIdx.x;
    if (k < 32) {
        float w = W1[k], bb = b1[k];
        int c = (w > 0.f) ? 1 : ((w < 0.f) ? -1 : 0);
        t[k] = (c == 0) ? INFINITY : (-bb / w);
        cls[k] = c;
    }
    __syncthreads();
    if (threadIdx.x == 0) {
        float a[32];
        for (int i = 0; i < 32; ++i) a[i] = t[i];
        for (int i = 1; i < 32; ++i) {
            float key = a[i]; int j = i - 1;
            while (j >= 0 && a[j] > key) { a[j + 1] = a[j]; --j; }
            a[j + 1] = key;
        }
        for (int i = 0; i < 32; ++i) { tso[i] = a[i]; ts[i] = a[i]; }
    }
    __syncthreads();
    if (k < 32) {
        float tk = t[k];
        int m = 0;
        for (int i = 0; i < 32; ++i) m += (tso[i] < tk) ? 1 : 0;
        mk[k] = m;
    }
}

// ---------------------------------------------------------------------------
// Count: per-chunk LDS histogram of dst buckets, then ~1 global atomic per
// nonzero (bucket,chunk) pair into per-graph totals. Both graphs in one grid.
// ---------------------------------------------------------------------------
__global__ void k_count2(const int* __restrict__ d1, const int* __restrict__ d2,
                         unsigned* __restrict__ Btot) {
    __shared__ unsigned cnt[NBKT];
    int g = blockIdx.x >> 8, blk = blockIdx.x & 255;
    const int* dst = g ? d2 : d1;
    for (int b = threadIdx.x; b < NBKT; b += blockDim.x) cnt[b] = 0u;
    __syncthreads();
    int e0 = blk * EPC;
    for (int e = e0 + threadIdx.x; e < e0 + EPC; e += blockDim.x)
        atomicAdd(&cnt[((unsigned)dst[e]) >> 7], 1u);
    __syncthreads();
    for (int b = threadIdx.x; b < NBKT; b += blockDim.x)
        if (cnt[b]) atomicAdd(&Btot[g * NBKT + b], cnt[b]);
}

// ---------------------------------------------------------------------------
// Scan bucket totals -> bucket bases; also init the run-allocation cursors.
// One block per graph; Hillis-Steele over 1024 (2 elems/thread).
// ---------------------------------------------------------------------------
__global__ void k_bscan(const unsigned* __restrict__ Btot,
                        unsigned* __restrict__ Bbase, unsigned* __restrict__ gcur) {
    __shared__ unsigned sc[1024];
    int g = blockIdx.x, t = threadIdx.x;   // 512 threads
    unsigned v0 = (t < NBKT) ? Btot[g * NBKT + t] : 0u;
    unsigned v1 = (t + 512 < NBKT) ? Btot[g * NBKT + t + 512] : 0u;
    sc[t] = v0; sc[t + 512] = v1;
    __syncthreads();
    for (int d = 1; d < 1024; d <<= 1) {
        unsigned a0 = (t >= d) ? sc[t - d] : 0u;
        unsigned a1 = (t + 512 >= d) ? sc[t + 512 - d] : 0u;
        __syncthreads();
        sc[t] += a0; sc[t + 512] += a1;
        __syncthreads();
    }
    if (t < NBKT)       { unsigned e = sc[t] - v0;       Bbase[g*NBKT+t]     = e; gcur[g*NBKT+t]     = e; }
    if (t + 512 < NBKT) { unsigned e = sc[t + 512] - v1; Bbase[g*NBKT+t+512] = e; gcur[g*NBKT+t+512] = e; }
}

// ---------------------------------------------------------------------------
// Scatter: per-chunk in-LDS counting sort by bucket, then run-coalesced
// writeout (each wave copies whole bucket runs -> contiguous global stores).
// One global atomic per nonzero (bucket,chunk) to allocate the run.
// ---------------------------------------------------------------------------
__global__ void k_scatter2(const int* __restrict__ s1, const int* __restrict__ d1,
                           const int* __restrict__ s2, const int* __restrict__ d2,
                           unsigned* __restrict__ gcur, unsigned* __restrict__ binned) {
    __shared__ unsigned cnt[NBKT];
    __shared__ unsigned pos[NBKT];
    __shared__ unsigned gbase[NBKT];
    __shared__ unsigned sc[1024];
    __shared__ unsigned payload[EPC];     // 50,000 B; block total 63,480 B < 64 KiB
    int g = blockIdx.x >> 8, blk = blockIdx.x & 255;
    const int* src = g ? s2 : s1;
    const int* dst = g ? d2 : d1;
    int t = threadIdx.x;                  // 512 threads
    for (int b = t; b < NBKT; b += 512) cnt[b] = 0u;
    __syncthreads();
    int e0 = blk * EPC;
    for (int e = e0 + t; e < e0 + EPC; e += 512)
        atomicAdd(&cnt[((unsigned)dst[e]) >> 7], 1u);
    __syncthreads();
    unsigned v0 = (t < NBKT) ? cnt[t] : 0u;
    unsigned v1 = (t + 512 < NBKT) ? cnt[t + 512] : 0u;
    sc[t] = v0; sc[t + 512] = v1;
    __syncthreads();
    for (int d = 1; d < 1024; d <<= 1) {
        unsigned a0 = (t >= d) ? sc[t - d] : 0u;
        unsigned a1 = (t + 512 >= d) ? sc[t + 512 - d] : 0u;
        __syncthreads();
        sc[t] += a0; sc[t + 512] += a1;
        __syncthreads();
    }
    if (t < NBKT) pos[t] = sc[t] - v0;
    if (t + 512 < NBKT) pos[t + 512] = sc[t + 512] - v1;
    __syncthreads();
    for (int b = t; b < NBKT; b += 512) {
        unsigned c = cnt[b];
        gbase[b] = c ? atomicAdd(&gcur[g * NBKT + b], c) : 0u;
        sc[b] = pos[b];                   // sc reused as local cursor
    }
    __syncthreads();
    for (int e = e0 + t; e < e0 + EPC; e += 512) {
        unsigned d = (unsigned)dst[e];
        unsigned p = atomicAdd(&sc[d >> 7], 1u);
        payload[p] = ((d & 127u) << SRC_BITS) | (unsigned)src[e];
    }
    __syncthreads();
    int wave = t >> 6, lane = t & 63;
    size_t gOff = (size_t)g * N_EDGES;
    for (int b = wave; b < NBKT; b += 8) {
        unsigned L = cnt[b], gb = gbase[b], lp = pos[b];
        for (unsigned l = lane; l < L; l += 64)
            binned[gOff + gb + l] = payload[lp + l];
    }
}

// ---------------------------------------------------------------------------
// Layer 1: per-bucket LDS segment-sum  s[i] = x[i] + sum_{j->i} x[j]
// ---------------------------------------------------------------------------
__global__ void k_layer1(const float* __restrict__ x1, const float* __restrict__ x2,
                         const unsigned* __restrict__ binned,
                         const unsigned* __restrict__ Bbase, const unsigned* __restrict__ Btot,
                         float* __restrict__ s_all) {
    __shared__ float sloc[NPB];
    int g = blockIdx.x / NBKT, b = blockIdx.x % NBKT;
    const float* x = g ? x2 : x1;
    const unsigned* bn = binned + (size_t)g * N_EDGES;
    float* s = s_all + (size_t)g * S_STRIDE;
    if (threadIdx.x < NPB) sloc[threadIdx.x] = 0.f;
    __syncthreads();
    unsigned beg = Bbase[g * NBKT + b], n = Btot[g * NBKT + b];
    for (unsigned i = threadIdx.x; i < n; i += blockDim.x) {
        unsigned p = bn[beg + i];
        atomicAdd(&sloc[p >> SRC_BITS], x[p & SRC_MASK]);
    }
    __syncthreads();
    if (threadIdx.x < NPB) {
        int node = b * NPB + threadIdx.x;
        if (node < N_NODES) s[node] = sloc[threadIdx.x] + x[node];
    }
}

// ---------------------------------------------------------------------------
// Layer 2 fused: per-bucket LDS (sum,count)[128][33] histogram of source
// scalars, then per-node suffix-scan reconstruction + W2 matvec + ReLU +
// register-accumulated pool flush. Both graphs in one grid.
// ---------------------------------------------------------------------------
__global__ void k_layer2(const float* __restrict__ s_all, const unsigned* __restrict__ binned,
                         const unsigned* __restrict__ Bbase, const unsigned* __restrict__ Btot,
                         const int* __restrict__ batch1, const int* __restrict__ batch2,
                         const float* __restrict__ ts, const int* __restrict__ mk,
                         const int* __restrict__ cls,
                         const float* __restrict__ W1, const float* __restrict__ b1,
                         const float* __restrict__ W2, const float* __restrict__ b2,
                         float* __restrict__ pool) {
    __shared__ float hS[NPB * NB];
    __shared__ float hC[NPB * NB];
    __shared__ float t_s[32];
    __shared__ float w2s[32 * 32];
    int tid = threadIdx.x;
    int g = blockIdx.x / NBKT, b = blockIdx.x % NBKT;
    const float* s = s_all + (size_t)g * S_STRIDE;
    const unsigned* bn = binned + (size_t)g * N_EDGES;
    const int* batch = g ? batch2 : batch1;
    float* poolg = pool + (size_t)g * NUM_GRAPHS * HIDDEN;

    for (int i = tid; i < NPB * NB; i += blockDim.x) { hS[i] = 0.f; hC[i] = 0.f; }
    if (tid < 32) t_s[tid] = ts[tid];
    for (int i = tid; i < 32 * 32; i += blockDim.x) w2s[i] = W2[i];
    __syncthreads();

    unsigned beg = Bbase[g * NBKT + b], n = Btot[g * NBKT + b];
    for (unsigned i = tid; i < n; i += blockDim.x) {
        unsigned p = bn[beg + i];
        float sv = s[p & SRC_MASK];
        unsigned dl = p >> SRC_BITS;
        int bk = 0;
        if (t_s[31] < sv) bk = 32;
        else {
#pragma unroll
            for (int st = 16; st; st >>= 1)
                if (bk + st <= 32 && t_s[bk + st - 1] < sv) bk += st;
        }
        atomicAdd(&hS[dl * NB + bk], sv);
        atomicAdd(&hC[dl * NB + bk], 1.0f);
    }
    __syncthreads();

    int wv = tid >> 6, lane = tid & 63, k = lane & 31;
    float w = W1[k], bb = b1[k], b2k = b2[k];
    int c = cls[k], m1 = mk[k] + 1;
    float pacc = 0.f; int curg = -1;
    for (int t = wv * 16; t < wv * 16 + 16; ++t) {
        int node = b * NPB + t;
        if (node >= N_NODES) break;                // uniform across the wave
        float Tsum = 0.f, Tcnt = 0.f;
        if (lane < NB) { Tsum = hS[t * NB + lane]; Tcnt = hC[t * NB + lane]; }
#pragma unroll
        for (int d2 = 1; d2 < 64; d2 <<= 1) {      // inclusive suffix sum
            float a  = __shfl_down(Tsum, d2, 64);
            float cc = __shfl_down(Tcnt, d2, 64);
            if (lane + d2 < 64) { Tsum += a; Tcnt += cc; }
        }
        float totS = __shfl(Tsum, 0, 64), totC = __shfl(Tcnt, 0, 64);
        float SA = __shfl(Tsum, m1, 64), CA = __shfl(Tcnt, m1, 64);
        float agg;
        if (c > 0)      agg = w * SA + bb * CA;
        else if (c < 0) agg = w * (totS - SA) + bb * (totC - CA);
        else            agg = fmaxf(bb, 0.f) * totC;
        float si = s[node];
        float v = fmaxf(fmaf(si, w, bb), 0.f) + agg;   // h_i[k] + agg2[i][k]
        float acc = b2k;
#pragma unroll
        for (int j = 0; j < 32; ++j)
            acc = fmaf(__shfl(v, j, 64), w2s[j * 32 + k], acc);
        float outk = fmaxf(acc, 0.f);
        int gg = batch[node];
        if (gg != curg) {
            if (curg >= 0 && lane < 32) atomicAdd(&poolg[curg * HIDDEN + k], pacc);
            pacc = 0.f; curg = gg;
        }
        pacc += outk;
    }
    if (curg >= 0 && lane < 32) atomicAdd(&poolg[curg * HIDDEN + k], pacc);
}

// ---------------------------------------------------------------------------
// out = |pool1 - pool2|
// ---------------------------------------------------------------------------
__global__ void k_absdiff(const float* __restrict__ pool, float* __restrict__ out) {
    int i = blockIdx.x * blockDim.x + threadIdx.x;
    if (i < NUM_GRAPHS * HIDDEN)
        out[i] = fabsf(pool[i] - pool[NUM_GRAPHS * HIDDEN + i]);
}

extern "C" void kernel_launch(void* const* d_in, const int* in_sizes, int n_in,
                              void* d_out, int out_size, void* d_ws, size_t ws_size,
                              hipStream_t stream) {
    const float* x1     = (const float*)d_in[0];
    const int*   ei1    = (const int*)d_in[1];   // [2, N_EDGES]: src row, dst row
    const int*   batch1 = (const int*)d_in[2];
    const float* x2     = (const float*)d_in[3];
    const int*   ei2    = (const int*)d_in[4];
    const int*   batch2 = (const int*)d_in[5];
    const float* W1     = (const float*)d_in[6];
    const float* b1     = (const float*)d_in[7];
    const float* W2     = (const float*)d_in[8];
    const float* b2     = (const float*)d_in[9];
    float* out = (float*)d_out;

    const int* src1 = ei1;            const int* dst1 = ei1 + N_EDGES;
    const int* src2 = ei2;            const int* dst2 = ei2 + N_EDGES;

    // workspace layout (~26.5 MB)
    char* ws = (char*)d_ws;
    size_t off = 0;
    auto alloc = [&](size_t bytes) { char* p = ws + off; off += (bytes + 255) & ~(size_t)255; return p; };
    float*    s_all  = (float*)   alloc((size_t)2 * S_STRIDE * 4);
    unsigned* binned = (unsigned*)alloc((size_t)2 * N_EDGES * 4);
    unsigned* Btot   = (unsigned*)alloc((size_t)2 * NBKT * 4);
    unsigned* Bbase  = (unsigned*)alloc((size_t)2 * NBKT * 4);
    unsigned* gcur   = (unsigned*)alloc((size_t)2 * NBKT * 4);
    float*    pool   = (float*)   alloc((size_t)2 * NUM_GRAPHS * HIDDEN * 4);
    float*    ts     = (float*)   alloc(256);
    int*      mk     = (int*)     alloc(256);
    int*      cls    = (int*)     alloc(256);

    hipMemsetAsync(Btot, 0, (size_t)2 * NBKT * 4, stream);
    hipMemsetAsync(pool, 0, (size_t)2 * NUM_GRAPHS * HIDDEN * 4, stream);
    k_setup<<<1, 64, 0, stream>>>(W1, b1, ts, mk, cls);

    k_count2  <<<2 * NCHUNK, 256, 0, stream>>>(dst1, dst2, Btot);
    k_bscan   <<<2, 512, 0, stream>>>(Btot, Bbase, gcur);
    k_scatter2<<<2 * NCHUNK, 512, 0, stream>>>(src1, dst1, src2, dst2, gcur, binned);
    k_layer1  <<<2 * NBKT, 512, 0, stream>>>(x1, x2, binned, Bbase, Btot, s_all);
    k_layer2  <<<2 * NBKT, 512, 0, stream>>>(s_all, binned, Bbase, Btot, batch1, batch2,
                                             ts, mk, cls, W1, b1, W2, b2, pool);

    k_absdiff<<<(NUM_GRAPHS * HIDDEN + 255) / 256, 256, 0, stream>>>(pool, out);
}

// Round 13
// 365.217 us; speedup vs baseline: 3.7800x; 1.3387x over previous
//
#include <hip/hip_runtime.h>
#include <hip/hip_bf16.h>
#include <math.h>

#define N_NODES 100000
#define N_EDGES 3200000
#define NUM_GRAPHS 128
#define HIDDEN 32
#define NB 33              // 32 sorted thresholds -> 33 value-buckets
#define NPB 128            // nodes per coarse bucket (dst >> 7)
#define NBKT 782           // ceil(100000 / 128)
#define NCHUNK 256         // edge chunks per graph
#define EPC (N_EDGES / NCHUNK)   // 12500 exactly
#define SRC_BITS 17
#define SRC_MASK 0x1FFFF
#define S_STRIDE 100096    // per-graph stride of s buffer (aligned)

typedef __attribute__((ext_vector_type(8))) short bf16x8;
typedef __attribute__((ext_vector_type(4))) float f32x4;

__device__ inline unsigned short f2bf(float f) {
    union { float f; unsigned u; } c; c.f = f;
    return (unsigned short)((c.u + 0x7fffu + ((c.u >> 16) & 1u)) >> 16);  // RNE
}

// ---------------------------------------------------------------------------
// Setup (once): thresholds t_k = -b1k/W1k sorted; per-k first-equal index m_k
// and sign class. relu(s*W1k+b1k) active iff s>t_k (W1k>0) or s<t_k (W1k<0).
// ---------------------------------------------------------------------------
__global__ void k_setup(const float* __restrict__ W1, const float* __restrict__ b1,
                        float* __restrict__ ts, int* __restrict__ mk,
                        int* __restrict__ cls) {
    __shared__ float t[32];
    __shared__ float tso[32];
    int k = threadIdx.x;
    if (k < 32) {
        float w = W1[k], bb = b1[k];
        int c = (w > 0.f) ? 1 : ((w < 0.f) ? -1 : 0);
        t[k] = (c == 0) ? INFINITY : (-bb / w);
        cls[k] = c;
    }
    __syncthreads();
    if (threadIdx.x == 0) {
        float a[32];
        for (int i = 0; i < 32; ++i) a[i] = t[i];
        for (int i = 1; i < 32; ++i) {
            float key = a[i]; int j = i - 1;
            while (j >= 0 && a[j] > key) { a[j + 1] = a[j]; --j; }
            a[j + 1] = key;
        }
        for (int i = 0; i < 32; ++i) { tso[i] = a[i]; ts[i] = a[i]; }
    }
    __syncthreads();
    if (k < 32) {
        float tk = t[k];
        int m = 0;
        for (int i = 0; i < 32; ++i) m += (tso[i] < tk) ? 1 : 0;
        mk[k] = m;
    }
}

// ---------------------------------------------------------------------------
// Count: per-chunk LDS histogram of dst buckets -> per-graph totals.
// ---------------------------------------------------------------------------
__global__ void k_count2(const int* __restrict__ d1, const int* __restrict__ d2,
                         unsigned* __restrict__ Btot) {
    __shared__ unsigned cnt[NBKT];
    int g = blockIdx.x >> 8, blk = blockIdx.x & 255;
    const int* dst = g ? d2 : d1;
    for (int b = threadIdx.x; b < NBKT; b += blockDim.x) cnt[b] = 0u;
    __syncthreads();
    int e0 = blk * EPC;
    for (int e = e0 + threadIdx.x; e < e0 + EPC; e += blockDim.x)
        atomicAdd(&cnt[((unsigned)dst[e]) >> 7], 1u);
    __syncthreads();
    for (int b = threadIdx.x; b < NBKT; b += blockDim.x)
        if (cnt[b]) atomicAdd(&Btot[g * NBKT + b], cnt[b]);
}

// ---------------------------------------------------------------------------
// Scan bucket totals -> bucket bases; init run-allocation cursors.
// ---------------------------------------------------------------------------
__global__ void k_bscan(const unsigned* __restrict__ Btot,
                        unsigned* __restrict__ Bbase, unsigned* __restrict__ gcur) {
    __shared__ unsigned sc[1024];
    int g = blockIdx.x, t = threadIdx.x;   // 512 threads
    unsigned v0 = (t < NBKT) ? Btot[g * NBKT + t] : 0u;
    unsigned v1 = (t + 512 < NBKT) ? Btot[g * NBKT + t + 512] : 0u;
    sc[t] = v0; sc[t + 512] = v1;
    __syncthreads();
    for (int d = 1; d < 1024; d <<= 1) {
        unsigned a0 = (t >= d) ? sc[t - d] : 0u;
        unsigned a1 = (t + 512 >= d) ? sc[t + 512 - d] : 0u;
        __syncthreads();
        sc[t] += a0; sc[t + 512] += a1;
        __syncthreads();
    }
    if (t < NBKT)       { unsigned e = sc[t] - v0;       Bbase[g*NBKT+t]     = e; gcur[g*NBKT+t]     = e; }
    if (t + 512 < NBKT) { unsigned e = sc[t + 512] - v1; Bbase[g*NBKT+t+512] = e; gcur[g*NBKT+t+512] = e; }
}

// ---------------------------------------------------------------------------
// Scatter: per-chunk in-LDS counting sort by bucket + run-coalesced writeout.
// ---------------------------------------------------------------------------
__global__ void k_scatter2(const int* __restrict__ s1, const int* __restrict__ d1,
                           const int* __restrict__ s2, const int* __restrict__ d2,
                           unsigned* __restrict__ gcur, unsigned* __restrict__ binned) {
    __shared__ unsigned cnt[NBKT];
    __shared__ unsigned pos[NBKT];
    __shared__ unsigned gbase[NBKT];
    __shared__ unsigned sc[1024];
    __shared__ unsigned payload[EPC];
    int g = blockIdx.x >> 8, blk = blockIdx.x & 255;
    const int* src = g ? s2 : s1;
    const int* dst = g ? d2 : d1;
    int t = threadIdx.x;                  // 512 threads
    for (int b = t; b < NBKT; b += 512) cnt[b] = 0u;
    __syncthreads();
    int e0 = blk * EPC;
    for (int e = e0 + t; e < e0 + EPC; e += 512)
        atomicAdd(&cnt[((unsigned)dst[e]) >> 7], 1u);
    __syncthreads();
    unsigned v0 = (t < NBKT) ? cnt[t] : 0u;
    unsigned v1 = (t + 512 < NBKT) ? cnt[t + 512] : 0u;
    sc[t] = v0; sc[t + 512] = v1;
    __syncthreads();
    for (int d = 1; d < 1024; d <<= 1) {
        unsigned a0 = (t >= d) ? sc[t - d] : 0u;
        unsigned a1 = (t + 512 >= d) ? sc[t + 512 - d] : 0u;
        __syncthreads();
        sc[t] += a0; sc[t + 512] += a1;
        __syncthreads();
    }
    if (t < NBKT) pos[t] = sc[t] - v0;
    if (t + 512 < NBKT) pos[t + 512] = sc[t + 512] - v1;
    __syncthreads();
    for (int b = t; b < NBKT; b += 512) {
        unsigned c = cnt[b];
        gbase[b] = c ? atomicAdd(&gcur[g * NBKT + b], c) : 0u;
        sc[b] = pos[b];                   // sc reused as local cursor
    }
    __syncthreads();
    for (int e = e0 + t; e < e0 + EPC; e += 512) {
        unsigned d = (unsigned)dst[e];
        unsigned p = atomicAdd(&sc[d >> 7], 1u);
        payload[p] = ((d & 127u) << SRC_BITS) | (unsigned)src[e];
    }
    __syncthreads();
    int wave = t >> 6, lane = t & 63;
    size_t gOff = (size_t)g * N_EDGES;
    for (int b = wave; b < NBKT; b += 8) {
        unsigned L = cnt[b], gb = gbase[b], lp = pos[b];
        for (unsigned l = lane; l < L; l += 64)
            binned[gOff + gb + l] = payload[lp + l];
    }
}

// ---------------------------------------------------------------------------
// Layer 1: per-bucket LDS segment-sum  s[i] = x[i] + sum_{j->i} x[j]
// ---------------------------------------------------------------------------
__global__ void k_layer1(const float* __restrict__ x1, const float* __restrict__ x2,
                         const unsigned* __restrict__ binned,
                         const unsigned* __restrict__ Bbase, const unsigned* __restrict__ Btot,
                         float* __restrict__ s_all) {
    __shared__ float sloc[NPB];
    int g = blockIdx.x / NBKT, b = blockIdx.x % NBKT;
    const float* x = g ? x2 : x1;
    const unsigned* bn = binned + (size_t)g * N_EDGES;
    float* s = s_all + (size_t)g * S_STRIDE;
    if (threadIdx.x < NPB) sloc[threadIdx.x] = 0.f;
    __syncthreads();
    unsigned beg = Bbase[g * NBKT + b], n = Btot[g * NBKT + b];
    for (unsigned i = threadIdx.x; i < n; i += blockDim.x) {
        unsigned p = bn[beg + i];
        atomicAdd(&sloc[p >> SRC_BITS], x[p & SRC_MASK]);
    }
    __syncthreads();
    if (threadIdx.x < NPB) {
        int node = b * NPB + threadIdx.x;
        if (node < N_NODES) s[node] = sloc[threadIdx.x] + x[node];
    }
}

// ---------------------------------------------------------------------------
// Layer 2 (shfl-free): transposed [33][128] LDS histogram -> serial per-node
// suffix scan -> per-(node,k) reconstruction in regs -> bf16 MFMA matvec
// (v[128x32] @ W2[32x32]) -> relu -> in-LDS 4-slot pool accumulation ->
// one global atomic per (graph,k) per block.
// ---------------------------------------------------------------------------
__global__ void k_layer2(const float* __restrict__ s_all, const unsigned* __restrict__ binned,
                         const unsigned* __restrict__ Bbase, const unsigned* __restrict__ Btot,
                         const int* __restrict__ batch1, const int* __restrict__ batch2,
                         const float* __restrict__ ts, const int* __restrict__ mk,
                         const int* __restrict__ cls,
                         const float* __restrict__ W1, const float* __restrict__ b1,
                         const float* __restrict__ W2, const float* __restrict__ b2,
                         float* __restrict__ pool) {
    __shared__ __align__(16) float hS[NB * NPB];
    __shared__ __align__(16) float hC[NB * NPB];   // aliased as v_lds after barrier
    __shared__ __align__(16) unsigned short w2t[32 * 40];  // W2^T, 80B-padded rows
    __shared__ float sloc[NPB];
    __shared__ int   batchL[NPB];
    __shared__ float t_sL[32], w1L[32], b1L[32], b2L[32];
    __shared__ int   m1L[32], clsL[32];
    __shared__ float poolacc[4 * 32];
    __shared__ int   slotgid[4];

    const int tid = threadIdx.x;
    const int g = blockIdx.x / NBKT, b = blockIdx.x % NBKT;
    const float* s = s_all + (size_t)g * S_STRIDE;
    const unsigned* bn = binned + (size_t)g * N_EDGES;
    const int* batch = g ? batch2 : batch1;
    float* poolg = pool + (size_t)g * NUM_GRAPHS * HIDDEN;

    // ---- init
    for (int i = tid; i < NB * NPB; i += 512) { hS[i] = 0.f; hC[i] = 0.f; }
    if (tid < 32) {
        t_sL[tid] = ts[tid];
        w1L[tid] = W1[tid]; b1L[tid] = b1[tid]; b2L[tid] = b2[tid];
        m1L[tid] = mk[tid] + 1; clsL[tid] = cls[tid];
    }
    if (tid < NPB) {
        int nodeG = b * NPB + tid;
        bool v = nodeG < N_NODES;
        sloc[tid]   = v ? s[nodeG] : 0.f;
        batchL[tid] = v ? batch[nodeG] : -1;
        poolacc[tid] = 0.f;                        // 4*32 == 128
    }
    if (tid < 4) slotgid[tid] = -1;
    for (int i = tid; i < 1024; i += 512) {
        int j = i & 31, k2 = i >> 5;
        w2t[k2 * 40 + j] = f2bf(W2[j * 32 + k2]); // w2t[col][k] = W2[k][col]
    }
    __syncthreads();

    // ---- edge histogram (transposed layout: hS[bucket*128 + dst_local])
    unsigned beg = Bbase[g * NBKT + b], n = Btot[g * NBKT + b];
    for (unsigned i = tid; i < n; i += 512) {
        unsigned p = bn[beg + i];
        float sv = s[p & SRC_MASK];
        unsigned dl = p >> SRC_BITS;
        int bk = 0;
        if (t_sL[31] < sv) bk = 32;
        else {
#pragma unroll
            for (int st = 16; st; st >>= 1)
                if (bk + st <= 32 && t_sL[bk + st - 1] < sv) bk += st;
        }
        atomicAdd(&hS[bk * NPB + dl], sv);
        atomicAdd(&hC[bk * NPB + dl], 1.0f);
    }
    __syncthreads();

    // ---- inclusive suffix scan along buckets, per node (coalesced, no shfl)
    if (tid < NPB) {
        int nd = tid; float suf = 0.f;
        for (int j = NB - 1; j >= 0; --j) { suf += hS[j * NPB + nd]; hS[j * NPB + nd] = suf; }
    } else if (tid < 2 * NPB) {
        int nd = tid - NPB; float suf = 0.f;
        for (int j = NB - 1; j >= 0; --j) { suf += hC[j * NPB + nd]; hC[j * NPB + nd] = suf; }
    }
    __syncthreads();

    // ---- v-compute: thread owns (node, kg) -> 8 consecutive k
    int nd = tid & 127, kg = tid >> 7;
    bool valid = batchL[nd] >= 0;
    float totS = hS[nd], totC = hC[nd];            // suffix at bucket 0 = totals
    float si = sloc[nd];
    float vf[8];
#pragma unroll
    for (int e = 0; e < 8; ++e) {
        int k = kg * 8 + e;
        int m1 = m1L[k], c = clsL[k];
        float w = w1L[k], bb = b1L[k];
        float SA = (m1 < NB) ? hS[m1 * NPB + nd] : 0.f;
        float CA = (m1 < NB) ? hC[m1 * NPB + nd] : 0.f;
        float agg;
        if (c > 0)      agg = w * SA + bb * CA;
        else if (c < 0) agg = w * (totS - SA) + bb * (totC - CA);
        else            agg = fmaxf(bb, 0.f) * totC;
        vf[e] = valid ? (fmaxf(fmaf(si, w, bb), 0.f) + agg) : 0.f;
    }
    __syncthreads();                               // all hC reads done

    // ---- write v as bf16 into v_lds (aliases hC), row stride 40 u16 (80B)
    unsigned short* v_lds = (unsigned short*)hC;
    {
        union { bf16x8 v; unsigned short u[8]; } pk;
#pragma unroll
        for (int e = 0; e < 8; ++e) pk.u[e] = f2bf(vf[e]);
        *(bf16x8*)&v_lds[nd * 40 + kg * 8] = pk.v;
    }
    __syncthreads();

    // ---- MFMA: wave w owns 16-node row-tile; 2 col-tiles (k2 0-15, 16-31)
    int wv = tid >> 6, lane = tid & 63;
    int kgrp = lane >> 4, col = lane & 15;
    bf16x8 afrag = *(const bf16x8*)&v_lds[(wv * 16 + col) * 40 + kgrp * 8]; // A[row=col-lane][k]
    bf16x8 bf0 = *(const bf16x8*)&w2t[col * 40 + kgrp * 8];
    bf16x8 bf1 = *(const bf16x8*)&w2t[(16 + col) * 40 + kgrp * 8];
    f32x4 zero = {0.f, 0.f, 0.f, 0.f};
    f32x4 acc0 = __builtin_amdgcn_mfma_f32_16x16x32_bf16(afrag, bf0, zero, 0, 0, 0);
    f32x4 acc1 = __builtin_amdgcn_mfma_f32_16x16x32_bf16(afrag, bf1, zero, 0, 0, 0);

    int g0 = batchL[wv * 16], g15 = batchL[wv * 16 + 15];
    bool uni = (g0 == g15) && (g0 >= 0);
    if (uni && lane == 0) slotgid[g0 & 3] = g0;
#pragma unroll
    for (int c = 0; c < 2; ++c) {
        f32x4 acc = c ? acc1 : acc0;
        int k2 = c * 16 + col;
        float b2v = b2L[k2];
        float o[4];
#pragma unroll
        for (int r = 0; r < 4; ++r) o[r] = fmaxf(acc[r] + b2v, 0.f);  // +b2, relu
        if (uni) {
            float s4 = o[0] + o[1] + o[2] + o[3];
            s4 += __shfl_xor(s4, 16, 64);
            s4 += __shfl_xor(s4, 32, 64);
            if (lane < 16) atomicAdd(&poolacc[(g0 & 3) * 32 + k2], s4);
        } else {   // graph boundary or padded nodes inside the tile (rare)
#pragma unroll
            for (int r = 0; r < 4; ++r) {
                int nr = wv * 16 + kgrp * 4 + r;   // C row = (lane>>4)*4 + r
                int gg = batchL[nr];
                if (gg >= 0) {
                    slotgid[gg & 3] = gg;
                    atomicAdd(&poolacc[(gg & 3) * 32 + k2], o[r]);
                }
            }
        }
    }
    __syncthreads();

    // ---- flush: one global atomic per (graph-slot, k)
    if (tid < 128) {
        int slot = tid >> 5, k2 = tid & 31;
        int gg = slotgid[slot];
        if (gg >= 0) atomicAdd(&poolg[gg * HIDDEN + k2], poolacc[slot * 32 + k2]);
    }
}

// ---------------------------------------------------------------------------
// out = |pool1 - pool2|
// ---------------------------------------------------------------------------
__global__ void k_absdiff(const float* __restrict__ pool, float* __restrict__ out) {
    int i = blockIdx.x * blockDim.x + threadIdx.x;
    if (i < NUM_GRAPHS * HIDDEN)
        out[i] = fabsf(pool[i] - pool[NUM_GRAPHS * HIDDEN + i]);
}

extern "C" void kernel_launch(void* const* d_in, const int* in_sizes, int n_in,
                              void* d_out, int out_size, void* d_ws, size_t ws_size,
                              hipStream_t stream) {
    const float* x1     = (const float*)d_in[0];
    const int*   ei1    = (const int*)d_in[1];   // [2, N_EDGES]: src row, dst row
    const int*   batch1 = (const int*)d_in[2];
    const float* x2     = (const float*)d_in[3];
    const int*   ei2    = (const int*)d_in[4];
    const int*   batch2 = (const int*)d_in[5];
    const float* W1     = (const float*)d_in[6];
    const float* b1     = (const float*)d_in[7];
    const float* W2     = (const float*)d_in[8];
    const float* b2     = (const float*)d_in[9];
    float* out = (float*)d_out;

    const int* src1 = ei1;            const int* dst1 = ei1 + N_EDGES;
    const int* src2 = ei2;            const int* dst2 = ei2 + N_EDGES;

    // workspace layout (~26.5 MB)
    char* ws = (char*)d_ws;
    size_t off = 0;
    auto alloc = [&](size_t bytes) { char* p = ws + off; off += (bytes + 255) & ~(size_t)255; return p; };
    float*    s_all  = (float*)   alloc((size_t)2 * S_STRIDE * 4);
    unsigned* binned = (unsigned*)alloc((size_t)2 * N_EDGES * 4);
    unsigned* Btot   = (unsigned*)alloc((size_t)2 * NBKT * 4);
    unsigned* Bbase  = (unsigned*)alloc((size_t)2 * NBKT * 4);
    unsigned* gcur   = (unsigned*)alloc((size_t)2 * NBKT * 4);
    float*    pool   = (float*)   alloc((size_t)2 * NUM_GRAPHS * HIDDEN * 4);
    float*    ts     = (float*)   alloc(256);
    int*      mk     = (int*)     alloc(256);
    int*      cls    = (int*)     alloc(256);

    hipMemsetAsync(Btot, 0, (size_t)2 * NBKT * 4, stream);
    hipMemsetAsync(pool, 0, (size_t)2 * NUM_GRAPHS * HIDDEN * 4, stream);
    k_setup<<<1, 64, 0, stream>>>(W1, b1, ts, mk, cls);

    k_count2  <<<2 * NCHUNK, 256, 0, stream>>>(dst1, dst2, Btot);
    k_bscan   <<<2, 512, 0, stream>>>(Btot, Bbase, gcur);
    k_scatter2<<<2 * NCHUNK, 512, 0, stream>>>(src1, dst1, src2, dst2, gcur, binned);
    k_layer1  <<<2 * NBKT, 512, 0, stream>>>(x1, x2, binned, Bbase, Btot, s_all);
    k_layer2  <<<2 * NBKT, 512, 0, stream>>>(s_all, binned, Bbase, Btot, batch1, batch2,
                                             ts, mk, cls, W1, b1, W2, b2, pool);

    k_absdiff<<<(NUM_GRAPHS * HIDDEN + 255) / 256, 256, 0, stream>>>(pool, out);
}

// Round 15
// 350.891 us; speedup vs baseline: 3.9344x; 1.0408x over previous
//
#include <hip/hip_runtime.h>
#include <hip/hip_bf16.h>
#include <math.h>

#define N_NODES 100000
#define N_EDGES 3200000
#define NUM_GRAPHS 128
#define HIDDEN 32
#define NB 33              // 32 sorted thresholds -> 33 value-buckets
#define NPB 128            // nodes per coarse bucket (dst >> 7)
#define NBKT 782           // ceil(100000 / 128)
#define NCHUNK 256         // edge chunks per graph
#define EPC (N_EDGES / NCHUNK)   // 12500 exactly
#define SRC_BITS 17
#define SRC_MASK 0x1FFFF
#define S_STRIDE 100096    // per-graph stride of s buffer (aligned)
#define CAP 4608           // bucket capacity: mean 4092, std 64 -> +8 sigma
#define INVALID 0xFFFFFFFFu

typedef __attribute__((ext_vector_type(8))) short bf16x8;
typedef __attribute__((ext_vector_type(4))) float f32x4;

__device__ inline unsigned short f2bf(float f) {
    union { float f; unsigned u; } c; c.f = f;
    return (unsigned short)((c.u + 0x7fffu + ((c.u >> 16) & 1u)) >> 16);  // RNE
}

// ---------------------------------------------------------------------------
// Setup (once): thresholds t_k = -b1k/W1k sorted; per-k first-equal index m_k
// and sign class. relu(s*W1k+b1k) active iff s>t_k (W1k>0) or s<t_k (W1k<0).
// ---------------------------------------------------------------------------
__global__ void k_setup(const float* __restrict__ W1, const float* __restrict__ b1,
                        float* __restrict__ ts, int* __restrict__ mk,
                        int* __restrict__ cls) {
    __shared__ float t[32];
    __shared__ float tso[32];
    int k = threadIdx.x;
    if (k < 32) {
        float w = W1[k], bb = b1[k];
        int c = (w > 0.f) ? 1 : ((w < 0.f) ? -1 : 0);
        t[k] = (c == 0) ? INFINITY : (-bb / w);
        cls[k] = c;
    }
    __syncthreads();
    if (threadIdx.x == 0) {
        float a[32];
        for (int i = 0; i < 32; ++i) a[i] = t[i];
        for (int i = 1; i < 32; ++i) {
            float key = a[i]; int j = i - 1;
            while (j >= 0 && a[j] > key) { a[j + 1] = a[j]; --j; }
            a[j + 1] = key;
        }
        for (int i = 0; i < 32; ++i) { tso[i] = a[i]; ts[i] = a[i]; }
    }
    __syncthreads();
    if (k < 32) {
        float tk = t[k];
        int m = 0;
        for (int i = 0; i < 32; ++i) m += (tso[i] < tk) ? 1 : 0;
        mk[k] = m;
    }
}

// ---------------------------------------------------------------------------
// Scatter (count-free): per-chunk in-LDS counting sort by bucket, run
// allocation via one global atomic per (bucket,chunk) into fixed-CAP slots,
// run-coalesced writeout. gcur starts at 0; after this kernel gcur[b] holds
// the bucket's edge count.
// ---------------------------------------------------------------------------
__global__ void k_scatter2(const int* __restrict__ s1, const int* __restrict__ d1,
                           const int* __restrict__ s2, const int* __restrict__ d2,
                           unsigned* __restrict__ gcur, unsigned* __restrict__ binned) {
    __shared__ unsigned cnt[NBKT];
    __shared__ unsigned pos[NBKT];
    __shared__ unsigned gbase[NBKT];
    __shared__ unsigned sc[1024];
    __shared__ unsigned payload[EPC];
    int g = blockIdx.x >> 8, blk = blockIdx.x & 255;
    const int* src = g ? s2 : s1;
    const int* dst = g ? d2 : d1;
    int t = threadIdx.x;                  // 512 threads
    for (int b = t; b < NBKT; b += 512) cnt[b] = 0u;
    __syncthreads();
    int e0 = blk * EPC;
    for (int e = e0 + t; e < e0 + EPC; e += 512)
        atomicAdd(&cnt[((unsigned)dst[e]) >> 7], 1u);
    __syncthreads();
    unsigned v0 = (t < NBKT) ? cnt[t] : 0u;
    unsigned v1 = (t + 512 < NBKT) ? cnt[t + 512] : 0u;
    sc[t] = v0; sc[t + 512] = v1;
    __syncthreads();
    for (int d = 1; d < 1024; d <<= 1) {
        unsigned a0 = (t >= d) ? sc[t - d] : 0u;
        unsigned a1 = (t + 512 >= d) ? sc[t + 512 - d] : 0u;
        __syncthreads();
        sc[t] += a0; sc[t + 512] += a1;
        __syncthreads();
    }
    if (t < NBKT) pos[t] = sc[t] - v0;
    if (t + 512 < NBKT) pos[t + 512] = sc[t + 512] - v1;
    __syncthreads();
    for (int b = t; b < NBKT; b += 512) {
        unsigned c = cnt[b];
        gbase[b] = c ? (b * CAP + atomicAdd(&gcur[g * NBKT + b], c)) : 0u;
        sc[b] = pos[b];                   // sc reused as local cursor
    }
    __syncthreads();
    for (int e = e0 + t; e < e0 + EPC; e += 512) {
        unsigned d = (unsigned)dst[e];
        unsigned p = atomicAdd(&sc[d >> 7], 1u);
        payload[p] = ((d & 127u) << SRC_BITS) | (unsigned)src[e];
    }
    __syncthreads();
    int wave = t >> 6, lane = t & 63;
    unsigned* bg = binned + (size_t)g * NBKT * CAP;
    for (int b = wave; b < NBKT; b += 8) {
        unsigned L = cnt[b], gb = gbase[b], lp = pos[b];
        for (unsigned l = lane; l < L; l += 64)
            bg[gb + l] = payload[lp + l];
    }
}

// ---------------------------------------------------------------------------
// Layer 1: per-bucket LDS segment-sum  s[i] = x[i] + sum_{j->i} x[j]
// MLP prefetch: 8 coalesced payload loads -> 8 independent x gathers -> atomics
// ---------------------------------------------------------------------------
__global__ void k_layer1(const float* __restrict__ x1, const float* __restrict__ x2,
                         const unsigned* __restrict__ binned,
                         const unsigned* __restrict__ gcur,
                         float* __restrict__ s_all) {
    __shared__ float sloc[NPB];
    int g = blockIdx.x / NBKT, b = blockIdx.x % NBKT;
    const float* x = g ? x2 : x1;
    const unsigned* bp = binned + (size_t)g * NBKT * CAP + (size_t)b * CAP;
    float* s = s_all + (size_t)g * S_STRIDE;
    int tid = threadIdx.x;
    if (tid < NPB) sloc[tid] = 0.f;
    __syncthreads();
    unsigned n = gcur[g * NBKT + b];
    for (unsigned base = 0; base < n; base += 4096) {
        unsigned p[8]; float xv[8];
#pragma unroll
        for (int e = 0; e < 8; ++e) {
            unsigned i = base + e * 512 + tid;
            p[e] = (i < n) ? bp[i] : INVALID;
        }
#pragma unroll
        for (int e = 0; e < 8; ++e)
            xv[e] = (p[e] != INVALID) ? x[p[e] & SRC_MASK] : 0.f;
#pragma unroll
        for (int e = 0; e < 8; ++e)
            if (p[e] != INVALID) atomicAdd(&sloc[p[e] >> SRC_BITS], xv[e]);
    }
    __syncthreads();
    if (tid < NPB) {
        int node = b * NPB + tid;
        if (node < N_NODES) s[node] = sloc[tid] + x[node];
    }
}

// ---------------------------------------------------------------------------
// Layer 2 (shfl-free, MLP-prefetched): transposed [33][128] LDS histogram ->
// serial per-node suffix scan -> per-(node,k) reconstruction -> bf16 MFMA
// matvec -> relu -> in-LDS 4-slot pool accumulation -> global atomic flush.
// ---------------------------------------------------------------------------
__global__ void k_layer2(const float* __restrict__ s_all, const unsigned* __restrict__ binned,
                         const unsigned* __restrict__ gcur,
                         const int* __restrict__ batch1, const int* __restrict__ batch2,
                         const float* __restrict__ ts, const int* __restrict__ mk,
                         const int* __restrict__ cls,
                         const float* __restrict__ W1, const float* __restrict__ b1,
                         const float* __restrict__ W2, const float* __restrict__ b2,
                         float* __restrict__ pool) {
    __shared__ __align__(16) float hS[NB * NPB];
    __shared__ __align__(16) float hC[NB * NPB];   // aliased as v_lds after barrier
    __shared__ __align__(16) unsigned short w2t[32 * 40];  // W2^T, 80B-padded rows
    __shared__ float sloc[NPB];
    __shared__ int   batchL[NPB];
    __shared__ float t_sL[32], w1L[32], b1L[32], b2L[32];
    __shared__ int   m1L[32], clsL[32];
    __shared__ float poolacc[4 * 32];
    __shared__ int   slotgid[4];

    const int tid = threadIdx.x;
    const int g = blockIdx.x / NBKT, b = blockIdx.x % NBKT;
    const float* s = s_all + (size_t)g * S_STRIDE;
    const unsigned* bp = binned + (size_t)g * NBKT * CAP + (size_t)b * CAP;
    const int* batch = g ? batch2 : batch1;
    float* poolg = pool + (size_t)g * NUM_GRAPHS * HIDDEN;

    // ---- init
    for (int i = tid; i < NB * NPB; i += 512) { hS[i] = 0.f; hC[i] = 0.f; }
    if (tid < 32) {
        t_sL[tid] = ts[tid];
        w1L[tid] = W1[tid]; b1L[tid] = b1[tid]; b2L[tid] = b2[tid];
        m1L[tid] = mk[tid] + 1; clsL[tid] = cls[tid];
    }
    if (tid < NPB) {
        int nodeG = b * NPB + tid;
        bool v = nodeG < N_NODES;
        sloc[tid]   = v ? s[nodeG] : 0.f;
        batchL[tid] = v ? batch[nodeG] : -1;
        poolacc[tid] = 0.f;                        // 4*32 == 128
    }
    if (tid < 4) slotgid[tid] = -1;
    for (int i = tid; i < 1024; i += 512) {
        int j = i & 31, k2 = i >> 5;
        w2t[k2 * 40 + j] = f2bf(W2[j * 32 + k2]); // w2t[col][k] = W2[k][col]
    }
    __syncthreads();

    // ---- edge histogram (transposed layout), 8-deep MLP prefetch
    unsigned n = gcur[g * NBKT + b];
    for (unsigned base = 0; base < n; base += 4096) {
        unsigned p[8]; float sv[8];
#pragma unroll
        for (int e = 0; e < 8; ++e) {
            unsigned i = base + e * 512 + tid;
            p[e] = (i < n) ? bp[i] : INVALID;
        }
#pragma unroll
        for (int e = 0; e < 8; ++e)
            sv[e] = (p[e] != INVALID) ? s[p[e] & SRC_MASK] : 0.f;
#pragma unroll
        for (int e = 0; e < 8; ++e) {
            if (p[e] == INVALID) continue;
            float v = sv[e];
            unsigned dl = p[e] >> SRC_BITS;
            int bk = 0;
            if (t_sL[31] < v) bk = 32;
            else {
#pragma unroll
                for (int st = 16; st; st >>= 1)
                    if (bk + st <= 32 && t_sL[bk + st - 1] < v) bk += st;
            }
            atomicAdd(&hS[bk * NPB + dl], v);
            atomicAdd(&hC[bk * NPB + dl], 1.0f);
        }
    }
    __syncthreads();

    // ---- inclusive suffix scan along buckets, per node (coalesced, no shfl)
    if (tid < NPB) {
        int nd = tid; float suf = 0.f;
        for (int j = NB - 1; j >= 0; --j) { suf += hS[j * NPB + nd]; hS[j * NPB + nd] = suf; }
    } else if (tid < 2 * NPB) {
        int nd = tid - NPB; float suf = 0.f;
        for (int j = NB - 1; j >= 0; --j) { suf += hC[j * NPB + nd]; hC[j * NPB + nd] = suf; }
    }
    __syncthreads();

    // ---- v-compute: thread owns (node, kg) -> 8 consecutive k
    int nd = tid & 127, kg = tid >> 7;
    bool valid = batchL[nd] >= 0;
    float totS = hS[nd], totC = hC[nd];            // suffix at bucket 0 = totals
    float si = sloc[nd];
    float vf[8];
#pragma unroll
    for (int e = 0; e < 8; ++e) {
        int k = kg * 8 + e;
        int m1 = m1L[k], c = clsL[k];
        float w = w1L[k], bb = b1L[k];
        float SA = (m1 < NB) ? hS[m1 * NPB + nd] : 0.f;
        float CA = (m1 < NB) ? hC[m1 * NPB + nd] : 0.f;
        float agg;
        if (c > 0)      agg = w * SA + bb * CA;
        else if (c < 0) agg = w * (totS - SA) + bb * (totC - CA);
        else            agg = fmaxf(bb, 0.f) * totC;
        vf[e] = valid ? (fmaxf(fmaf(si, w, bb), 0.f) + agg) : 0.f;
    }
    __syncthreads();                               // all hC reads done

    // ---- write v as bf16 into v_lds (aliases hC), row stride 40 u16 (80B)
    unsigned short* v_lds = (unsigned short*)hC;
    {
        union { bf16x8 v; unsigned short u[8]; } pk;
#pragma unroll
        for (int e = 0; e < 8; ++e) pk.u[e] = f2bf(vf[e]);
        *(bf16x8*)&v_lds[nd * 40 + kg * 8] = pk.v;
    }
    __syncthreads();

    // ---- MFMA: wave w owns 16-node row-tile; 2 col-tiles (k2 0-15, 16-31)
    int wv = tid >> 6, lane = tid & 63;
    int kgrp = lane >> 4, col = lane & 15;
    bf16x8 afrag = *(const bf16x8*)&v_lds[(wv * 16 + col) * 40 + kgrp * 8]; // A[row=col-lane][k]
    bf16x8 bf0 = *(const bf16x8*)&w2t[col * 40 + kgrp * 8];
    bf16x8 bf1 = *(const bf16x8*)&w2t[(16 + col) * 40 + kgrp * 8];
    f32x4 zero = {0.f, 0.f, 0.f, 0.f};
    f32x4 acc0 = __builtin_amdgcn_mfma_f32_16x16x32_bf16(afrag, bf0, zero, 0, 0, 0);
    f32x4 acc1 = __builtin_amdgcn_mfma_f32_16x16x32_bf16(afrag, bf1, zero, 0, 0, 0);

    int g0 = batchL[wv * 16], g15 = batchL[wv * 16 + 15];
    bool uni = (g0 == g15) && (g0 >= 0);
    if (uni && lane == 0) slotgid[g0 & 3] = g0;
#pragma unroll
    for (int c = 0; c < 2; ++c) {
        f32x4 acc = c ? acc1 : acc0;
        int k2 = c * 16 + col;
        float b2v = b2L[k2];
        float o[4];
#pragma unroll
        for (int r = 0; r < 4; ++r) o[r] = fmaxf(acc[r] + b2v, 0.f);  // +b2, relu
        if (uni) {
            float s4 = o[0] + o[1] + o[2] + o[3];
            s4 += __shfl_xor(s4, 16, 64);
            s4 += __shfl_xor(s4, 32, 64);
            if (lane < 16) atomicAdd(&poolacc[(g0 & 3) * 32 + k2], s4);
        } else {   // graph boundary or padded nodes inside the tile (rare)
#pragma unroll
            for (int r = 0; r < 4; ++r) {
                int nr = wv * 16 + kgrp * 4 + r;   // C row = (lane>>4)*4 + r
                int gg = batchL[nr];
                if (gg >= 0) {
                    slotgid[gg & 3] = gg;
                    atomicAdd(&poolacc[(gg & 3) * 32 + k2], o[r]);
                }
            }
        }
    }
    __syncthreads();

    // ---- flush: one global atomic per (graph-slot, k)
    if (tid < 128) {
        int slot = tid >> 5, k2 = tid & 31;
        int gg = slotgid[slot];
        if (gg >= 0) atomicAdd(&poolg[gg * HIDDEN + k2], poolacc[slot * 32 + k2]);
    }
}

// ---------------------------------------------------------------------------
// out = |pool1 - pool2|
// ---------------------------------------------------------------------------
__global__ void k_absdiff(const float* __restrict__ pool, float* __restrict__ out) {
    int i = blockIdx.x * blockDim.x + threadIdx.x;
    if (i < NUM_GRAPHS * HIDDEN)
        out[i] = fabsf(pool[i] - pool[NUM_GRAPHS * HIDDEN + i]);
}

extern "C" void kernel_launch(void* const* d_in, const int* in_sizes, int n_in,
                              void* d_out, int out_size, void* d_ws, size_t ws_size,
                              hipStream_t stream) {
    const float* x1     = (const float*)d_in[0];
    const int*   ei1    = (const int*)d_in[1];   // [2, N_EDGES]: src row, dst row
    const int*   batch1 = (const int*)d_in[2];
    const float* x2     = (const float*)d_in[3];
    const int*   ei2    = (const int*)d_in[4];
    const int*   batch2 = (const int*)d_in[5];
    const float* W1     = (const float*)d_in[6];
    const float* b1     = (const float*)d_in[7];
    const float* W2     = (const float*)d_in[8];
    const float* b2     = (const float*)d_in[9];
    float* out = (float*)d_out;

    const int* src1 = ei1;            const int* dst1 = ei1 + N_EDGES;
    const int* src2 = ei2;            const int* dst2 = ei2 + N_EDGES;

    // workspace layout (~30 MB)
    char* ws = (char*)d_ws;
    size_t off = 0;
    auto alloc = [&](size_t bytes) { char* p = ws + off; off += (bytes + 255) & ~(size_t)255; return p; };
    float*    s_all  = (float*)   alloc((size_t)2 * S_STRIDE * 4);
    unsigned* binned = (unsigned*)alloc((size_t)2 * NBKT * CAP * 4);   // 28.8 MB
    unsigned* gcur   = (unsigned*)alloc((size_t)2 * NBKT * 4);
    float*    pool   = (float*)   alloc((size_t)2 * NUM_GRAPHS * HIDDEN * 4);
    float*    ts     = (float*)   alloc(256);
    int*      mk     = (int*)     alloc(256);
    int*      cls    = (int*)     alloc(256);

    hipMemsetAsync(gcur, 0, (size_t)2 * NBKT * 4, stream);
    hipMemsetAsync(pool, 0, (size_t)2 * NUM_GRAPHS * HIDDEN * 4, stream);
    k_setup<<<1, 64, 0, stream>>>(W1, b1, ts, mk, cls);

    k_scatter2<<<2 * NCHUNK, 512, 0, stream>>>(src1, dst1, src2, dst2, gcur, binned);
    k_layer1  <<<2 * NBKT, 512, 0, stream>>>(x1, x2, binned, gcur, s_all);
    k_layer2  <<<2 * NBKT, 512, 0, stream>>>(s_all, binned, gcur, batch1, batch2,
                                             ts, mk, cls, W1, b1, W2, b2, pool);

    k_absdiff<<<(NUM_GRAPHS * HIDDEN + 255) / 256, 256, 0, stream>>>(pool, out);
}